// Round 8
// baseline (599.786 us; speedup 1.0000x reference)
//
#include <hip/hip_runtime.h>
#include <cstddef>

// LfExpert: bf16 MFMA implicit-GEMM. NHWC bf16 activations, fp32 accum.
// R8: conv3 staging made WAVE-PRIVATE (each wave stages its own 6 input rows
// into a private 13.8KB LDS region; halo duplicated) -> no __syncthreads, no
// block-wide vmcnt drain. Tile back to R5's 16x16, grid (64,8), bounds(256,2).
// mm1 keeps R7's hoisted loads. absmax-stable epilogues unchanged.

#define HW2 16384
typedef short short8 __attribute__((ext_vector_type(8)));
typedef float f32x4 __attribute__((ext_vector_type(4)));
typedef unsigned short ushort_t;
typedef unsigned int uint_t;

enum { M_PLAIN = 0, M_ADD2 = 1, M_SIGEXP = 2, M_COUPLE = 3, M_LRELU = 4, M_EACC = 5 };

__device__ __forceinline__ float bf2f(ushort_t u) {
  return __uint_as_float(((uint_t)u) << 16);
}
__device__ __forceinline__ ushort_t f2bf(float f) {
  uint_t u = __float_as_uint(f);
  u += 0x7fffu + ((u >> 16) & 1u);  // RNE
  return (ushort_t)(u >> 16);
}
__device__ __forceinline__ uint_t pack2(float a, float b) {
  return (uint_t)f2bf(a) | ((uint_t)f2bf(b) << 16);
}
__device__ __forceinline__ void ld4bf(const ushort_t* p, float* o) {
  uint2 d = *(const uint2*)p;
  o[0] = bf2f((ushort_t)(d.x & 0xffff)); o[1] = bf2f((ushort_t)(d.x >> 16));
  o[2] = bf2f((ushort_t)(d.y & 0xffff)); o[3] = bf2f((ushort_t)(d.y >> 16));
}
__device__ __forceinline__ void st4bf(ushort_t* p, const float* v) {
  uint2 st; st.x = pack2(v[0], v[1]); st.y = pack2(v[2], v[3]);
  *(uint2*)p = st;
}
__device__ __forceinline__ void gload_lds16(const void* g, void* l) {
  __builtin_amdgcn_global_load_lds(
      (const __attribute__((address_space(1))) void*)g,
      (__attribute__((address_space(3))) void*)l, 16, 0, 0);
}

// ---------- weight transform: [co][ci][3][3] f32 -> chunked bf16 ----------
// chunk c = (tap*2+h)*4+n, 512 ushorts each; lane offset (col*4+krow)*8+e.
__global__ void wtrans_kernel(const float* __restrict__ bw1, const float* __restrict__ bw2,
                              const float* __restrict__ ew1, const float* __restrict__ ew2,
                              ushort_t* __restrict__ wbuf) {
  int idx = blockIdx.x * 256 + threadIdx.x;  // < 516096
  int ci = idx & 63; int co = (idx >> 6) & 63;
  int rest = idx >> 12;            // conv*9 + tap, < 126
  int tap = rest % 9; int conv = rest / 9;
  const float* src;
  if (conv < 3)       src = bw1 + (size_t)conv * 36864;
  else if (conv < 6)  src = bw2 + (size_t)(conv - 3) * 36864;
  else if (conv < 10) src = ew1 + (size_t)(conv - 6) * 36864;
  else                src = ew2 + (size_t)(conv - 10) * 36864;
  float v = src[(co * 64 + ci) * 9 + tap];
  int n = co >> 4, col = co & 15;
  int h = ci >> 5, krow = (ci >> 3) & 3, e = ci & 7;
  int pos = conv * 36864 + (((tap * 2 + h) * 4 + n) << 9) + ((col << 2) + krow) * 8 + e;
  wbuf[pos] = f2bf(v);
}

__global__ void cvt_kernel(const float* __restrict__ s, ushort_t* __restrict__ d, int n) {
  int i = blockIdx.x * 256 + threadIdx.x;
  if (i < n) d[i] = f2bf(s[i]);
}

// ---------- x NCHW f32 -> NHWC bf16 (C=128) ----------
__global__ __launch_bounds__(256) void xtrans_kernel(const float* __restrict__ x,
                                                     ushort_t* __restrict__ xh) {
  int b = blockIdx.y;
  int oct = blockIdx.x >> 6;                    // 0..15
  int p = ((blockIdx.x & 63) << 8) + threadIdx.x;  // 0..16383
  short8 v;
#pragma unroll
  for (int j = 0; j < 8; ++j)
    v[j] = (short)f2bf(x[((size_t)(b * 128 + oct * 8 + j)) * HW2 + p]);
  *(short8*)(xh + ((size_t)b * HW2 + p) * 128 + oct * 8) = v;
}

// ---------- 3x3 conv 64->64 via MFMA, fused epilogues, wave-private LDS ----------
// Tile: 16 rows x 16 cols x 64 co per block; wave w owns output rows 4w..4w+3.
// Wave-private region: 6 input rows x 18 x x 8 oct-slots, slot=(r*18+xx)*8+octS,
// octS = oct ^ (xx&7); 13824 B per wave, 55296 B total. No __syncthreads.
template <int MODE, bool INORM>
__global__ __launch_bounds__(256, 2) void conv3_kernel(
    const ushort_t* __restrict__ in, int icstr, int icoff,
    const ushort_t* __restrict__ wgt, const float* __restrict__ bias,
    void* __restrict__ outv, int ocstr, int ocoff,
    const ushort_t* __restrict__ r1, int r1cstr, int r1off,
    const ushort_t* __restrict__ r2, int r2cstr, int r2off,
    const ushort_t* __restrict__ mul, int mcstr, int moff,
    const float* __restrict__ kh, const float* __restrict__ cof, int expert) {
  int b = blockIdx.y;
  float cv = 0.f; bool first = false;
  if (MODE == M_LRELU || MODE == M_EACC) {
    cv = cof[b * 4 + expert];
    if (cv == 0.f) return;  // block-uniform skip
    if (MODE == M_EACC) {
      first = true;
      for (int e2 = 0; e2 < expert; ++e2) if (cof[b * 4 + e2] != 0.f) first = false;
    }
  }
  int tile = blockIdx.x;
  int ty0 = (tile >> 3) << 4;   // 8 y-tiles x 16 rows
  int tx0 = (tile & 7) << 4;    // 8 x-tiles x 16 cols
  int t = threadIdx.x;
  int lane = t & 63, w = t >> 6;

  __shared__ __align__(16) ushort_t sm[4 * 864 * 8];  // 55296 B, 13824 B/wave
  char* smb = (char*)sm + w * 13824;
  int ry0 = ty0 + (w << 2) - 1;  // global row of wave-local r=0

  if (!INORM) {
    // zero-fill this wave's OOB halo slots
#pragma unroll
    for (int k = 0; k < 14; ++k) {
      int j = (k << 6) + lane;
      if (j < 864) {
        int r = j / 144, rem = j - r * 144;
        int xx = rem >> 3;
        int gy = ry0 + r, gx = tx0 + xx - 1;
        if ((unsigned)gy >= 128u || (unsigned)gx >= 128u) {
          short8 z = {0, 0, 0, 0, 0, 0, 0, 0};
          *(short8*)(smb + (j << 4)) = z;
        }
      }
    }
    // async staging into this wave's private region (swizzle on global addr)
#pragma unroll
    for (int k = 0; k < 14; ++k) {
      int j = (k << 6) + lane;
      if (j < 864) {
        int r = j / 144, rem = j - r * 144;
        int xx = rem >> 3, octS = rem & 7;
        int oct = octS ^ (xx & 7);
        int gy = ry0 + r, gx = tx0 + xx - 1;
        if ((unsigned)gy < 128u && (unsigned)gx < 128u) {
          const ushort_t* gp =
              in + ((size_t)b * HW2 + (gy << 7) + gx) * icstr + icoff + oct * 8;
          gload_lds16(gp, smb + (k << 10));
        }
      }
    }
    // wave-local drain of the async queue (replaces __syncthreads)
    asm volatile("s_waitcnt vmcnt(0)" ::: "memory");
  } else {
    // register staging (instance-norm applied in flight, padding stays 0)
    short8 v[14];
#pragma unroll
    for (int k = 0; k < 14; ++k) {
      int j = (k << 6) + lane;
      short8 vv = {0, 0, 0, 0, 0, 0, 0, 0};
      if (j < 864) {
        int r = j / 144, rem = j - r * 144;
        int xx = rem >> 3, octS = rem & 7;
        int oct = octS ^ (xx & 7);
        int gy = ry0 + r, gx = tx0 + xx - 1;
        if ((unsigned)gy < 128u && (unsigned)gx < 128u) {
          vv = *(const short8*)(in + ((size_t)b * HW2 + (gy << 7) + gx) * icstr + icoff + oct * 8);
          if (oct < 4) {  // c<32 normalized; zero-padding NOT normalized
            const float* khp = kh + (b * 32 + oct * 8) * 2;
#pragma unroll
            for (int jq = 0; jq < 8; ++jq) {
              float f = bf2f((ushort_t)vv[jq]);
              vv[jq] = (short)f2bf(f * khp[jq * 2] + khp[jq * 2 + 1]);
            }
          }
        }
      }
      v[k] = vv;
    }
#pragma unroll
    for (int k = 0; k < 14; ++k) {
      int j = (k << 6) + lane;
      if (j < 864) *(short8*)(smb + (j << 4)) = v[k];
    }
  }

  int col = lane & 15, krow = lane >> 4;
  int wofs = ((col << 2) + krow) * 8;  // lane offset within 512-ushort chunk
  f32x4 acc[4][4] = {};

#pragma unroll
  for (int tap = 0; tap < 9; ++tap) {
    const int dy = tap / 3, dx = tap - dy * 3;
#pragma unroll
    for (int h = 0; h < 2; ++h) {
      short8 af[4];
      const ushort_t* wbase = wgt + (((tap * 2 + h) * 4) << 9) + wofs;
#pragma unroll
      for (int n = 0; n < 4; ++n) af[n] = *(const short8*)(wbase + (n << 9));
      short8 bfr[4];
#pragma unroll
      for (int s = 0; s < 4; ++s) {
        int r = s + dy, xx = col + dx;   // wave-local row
        bfr[s] = *(const short8*)(smb +
                 (((r * 18 + xx) * 8 + ((h * 4 + krow) ^ (xx & 7))) << 4));
      }
#pragma unroll
      for (int s = 0; s < 4; ++s)
#pragma unroll
        for (int n = 0; n < 4; ++n)
          acc[s][n] = __builtin_amdgcn_mfma_f32_16x16x32_bf16(af[n], bfr[s], acc[s][n], 0, 0, 0);
    }
  }

#pragma unroll
  for (int s = 0; s < 4; ++s) {
    int py = ty0 + (w << 2) + s;
    size_t pix = (size_t)b * HW2 + (py << 7) + tx0 + col;
#pragma unroll
    for (int n = 0; n < 4; ++n) {
      int cb = n * 16 + krow * 4;
      float v[4];
#pragma unroll
      for (int r = 0; r < 4; ++r) v[r] = acc[s][n][r] + bias[cb + r];
      if (MODE == M_PLAIN) {
        st4bf((ushort_t*)outv + pix * ocstr + ocoff + cb, v);
      } else if (MODE == M_ADD2) {
        float a[4], bb[4];
        ld4bf(r1 + pix * r1cstr + r1off + cb, a);
        ld4bf(r2 + pix * r2cstr + r2off + cb, bb);
#pragma unroll
        for (int r = 0; r < 4; ++r) v[r] += a[r] + bb[r];
        st4bf((ushort_t*)outv + pix * ocstr + ocoff + cb, v);
      } else if (MODE == M_SIGEXP) {
        float a[4];
        ld4bf(r1 + pix * r1cstr + r1off + cb, a);
#pragma unroll
        for (int r = 0; r < 4; ++r) {
          float tt = v[r] + a[r];
          float sg = 1.f / (1.f + __expf(-tt));
          v[r] = __expf(1.6f * sg - 0.8f);
        }
        st4bf((ushort_t*)outv + pix * ocstr + ocoff + cb, v);
      } else if (MODE == M_COUPLE) {
        float a[4], bb[4], mm[4];
        ld4bf(r1 + pix * r1cstr + r1off + cb, a);
        ld4bf(r2 + pix * r2cstr + r2off + cb, bb);
        ld4bf(mul + pix * mcstr + moff + cb, mm);
#pragma unroll
        for (int r = 0; r < 4; ++r) v[r] += a[r] + bb[r] * mm[r];
        st4bf((ushort_t*)outv + pix * ocstr + ocoff + cb, v);
      } else if (MODE == M_LRELU) {
#pragma unroll
        for (int r = 0; r < 4; ++r) v[r] = v[r] > 0.f ? v[r] : 0.2f * v[r];
        st4bf((ushort_t*)outv + pix * ocstr + ocoff + cb, v);
      } else if (MODE == M_EACC) {
        float a[4];
        ld4bf(r1 + pix * r1cstr + r1off + cb, a);  // xf
        f32x4 val;
#pragma unroll
        for (int r = 0; r < 4; ++r) val[r] = cv * (v[r] + a[r]);
        float* ap = (float*)outv + pix * 64 + cb;
        if (first) *(f32x4*)ap = val;
        else { f32x4 old = *(f32x4*)ap; *(f32x4*)ap = old + val; }
      }
    }
  }
}

// ---------- 1x1 conv (K=128) via MFMA, software-pipelined ----------
template <int NF>  // NF = NCO/16
__global__ __launch_bounds__(256, 2) void mm1_kernel(
    const ushort_t* __restrict__ in, int icstr,
    const ushort_t* __restrict__ wgt, const float* __restrict__ bias,
    ushort_t* __restrict__ out, int ocstr) {
  int b = blockIdx.y;
  int p0 = blockIdx.x << 7;
  int t = threadIdx.x, lane = t & 63, w = t >> 6;
  int col = lane & 15, krow = lane >> 4;
  size_t pixb = (size_t)b * HW2 + p0 + w * 32;
  // hoist ALL activation loads: 8 independent 16B loads in flight
  short8 bfr[4][2];
#pragma unroll
  for (int kk = 0; kk < 4; ++kk)
#pragma unroll
    for (int s = 0; s < 2; ++s)
      bfr[kk][s] = *(const short8*)(in + (pixb + s * 16 + col) * icstr + kk * 32 + krow * 8);
  f32x4 acc[2][NF] = {};
#pragma unroll
  for (int kk = 0; kk < 4; ++kk) {
#pragma unroll
    for (int n = 0; n < NF; ++n) {
      short8 af = *(const short8*)(wgt + (n * 16 + col) * 128 + kk * 32 + krow * 8);
#pragma unroll
      for (int s = 0; s < 2; ++s)
        acc[s][n] = __builtin_amdgcn_mfma_f32_16x16x32_bf16(af, bfr[kk][s], acc[s][n], 0, 0, 0);
    }
  }
#pragma unroll
  for (int s = 0; s < 2; ++s) {
    size_t pix = pixb + s * 16 + col;
#pragma unroll
    for (int n = 0; n < NF; ++n) {
      int cb = n * 16 + krow * 4;
      float v[4];
#pragma unroll
      for (int r = 0; r < 4; ++r) v[r] = acc[s][n][r] + (bias ? bias[cb + r] : 0.f);
      st4bf(out + pix * ocstr + cb, v);
    }
  }
}

// ---------- instance-norm partial reduce over h (c<32) ----------
__global__ __launch_bounds__(256) void ireduce_kernel(const ushort_t* __restrict__ h,
                                                      float* __restrict__ part) {
  int b = blockIdx.y, chunk = blockIdx.x, t = threadIdx.x;
  int c = t & 31, g = t >> 5;
  float s = 0.f, q = 0.f;
  const ushort_t* base = h + ((size_t)b * HW2 + chunk * 512) * 64 + c;
  for (int i = 0; i < 64; ++i) {
    float f = bf2f(base[(g + i * 8) * 64]);
    s += f; q += f * f;
  }
  __shared__ float ls[8][32], lq[8][32];
  ls[g][c] = s; lq[g][c] = q;
  __syncthreads();
  if (t < 32) {
    float S = 0.f, Q = 0.f;
    for (int gg = 0; gg < 8; ++gg) { S += ls[gg][t]; Q += lq[gg][t]; }
    float* pp = part + ((b * 32 + chunk) * 32 + t) * 2;
    pp[0] = S; pp[1] = Q;
  }
}

__global__ void istat_kernel(const float* __restrict__ part, const float* __restrict__ nw,
                             const float* __restrict__ nb, float* __restrict__ kh) {
  int t = threadIdx.x; if (t >= 256) return;
  int b = t >> 5, c = t & 31;
  float S = 0.f, Q = 0.f;
  for (int ch = 0; ch < 32; ++ch) {
    const float* pp = part + ((b * 32 + ch) * 32 + c) * 2;
    S += pp[0]; Q += pp[1];
  }
  float m = S * (1.f / 16384.f);
  float var = Q * (1.f / 16384.f) - m * m;
  float k = nw[c] * rsqrtf(var + 1e-5f);
  kh[(b * 32 + c) * 2] = k;
  kh[(b * 32 + c) * 2 + 1] = nb[c] - m * k;
}

// ---------- pooling partials (sum, max) over xf ----------
__global__ __launch_bounds__(256) void preduce_kernel(const ushort_t* __restrict__ xf,
                                                      float* __restrict__ part2) {
  int b = blockIdx.y, chunk = blockIdx.x, t = threadIdx.x;
  int c = t & 63, g = t >> 6;
  float s = 0.f, mx = -3.4e38f;
  const ushort_t* base = xf + ((size_t)b * HW2 + chunk * 512) * 64 + c;
  for (int i = 0; i < 128; ++i) {
    float f = bf2f(base[(g + i * 4) * 64]);
    s += f; mx = fmaxf(mx, f);
  }
  __shared__ float ls[4][64], lm[4][64];
  ls[g][c] = s; lm[g][c] = mx;
  __syncthreads();
  if (t < 64) {
    float S = ls[0][t] + ls[1][t] + ls[2][t] + ls[3][t];
    float M = fmaxf(fmaxf(lm[0][t], lm[1][t]), fmaxf(lm[2][t], lm[3][t]));
    float* pp = part2 + ((b * 32 + chunk) * 64 + t) * 2;
    pp[0] = S; pp[1] = M;
  }
}

__global__ void pool2_kernel(const float* __restrict__ part2, float* __restrict__ g) {
  int t = blockIdx.x * blockDim.x + threadIdx.x;
  if (t >= 512) return;
  int b = t >> 6, c = t & 63;
  float S = 0.f, M = -3.4e38f;
  for (int ch = 0; ch < 32; ++ch) {
    const float* pp = part2 + ((b * 32 + ch) * 64 + c) * 2;
    S += pp[0]; M = fmaxf(M, pp[1]);
  }
  g[t] = M + S * (1.f / 16384.f);
}

// ---------- gating ----------
__global__ void gate_kernel(const float* __restrict__ g, const float* __restrict__ gw0,
                            const float* __restrict__ gb0, const float* __restrict__ gw1,
                            const float* __restrict__ gb1, float* __restrict__ cof) {
  int b = threadIdx.x;
  if (b >= 8) return;
  float lg[4], noise[4];
  for (int e = 0; e < 4; ++e) {
    float a0 = gb0[e], a1 = gb1[e];
    for (int c = 0; c < 64; ++c) {
      float gv = g[b * 64 + c];
      a0 += gv * gw0[e * 64 + c];
      a1 += gv * gw1[e * 64 + c];
    }
    lg[e] = a1 > 0.f ? a1 : 0.2f * a1;
    noise[e] = fmaxf(a0, 0.f) + log1pf(expf(-fabsf(a0)));
  }
  float nm = 0.25f * (noise[0] + noise[1] + noise[2] + noise[3]);
  float vs = 0.f;
  for (int e = 0; e < 4; ++e) { float d = noise[e] - nm; vs += d * d; }
  float ns = sqrtf(vs / 3.f);
  float sc[4];
  for (int e = 0; e < 4; ++e) sc[e] = lg[e] + (noise[e] - nm) / ns;
  int i1 = 0;
  for (int e = 1; e < 4; ++e) if (sc[e] > sc[i1]) i1 = e;
  int i2 = -1;
  for (int e = 0; e < 4; ++e) if (e != i1 && (i2 < 0 || sc[e] > sc[i2])) i2 = e;
  float mx = fmaxf(lg[i1], lg[i2]);
  float e1 = expf(lg[i1] - mx), e2 = expf(lg[i2] - mx);
  float d = e1 + e2;
  for (int e = 0; e < 4; ++e) cof[b * 4 + e] = 0.f;
  cof[b * 4 + i1] = e1 / d;
  cof[b * 4 + i2] = e2 / d;
}

// ---------- NHWC f32 acc -> NCHW f32 out ----------
__global__ __launch_bounds__(256) void nchw_kernel(const float* __restrict__ acc,
                                                   float* __restrict__ out) {
  int b = blockIdx.y, pix0 = blockIdx.x << 6, t = threadIdx.x;
  __shared__ float ts[64][68];
  for (int i = t; i < 1024; i += 256) {
    int px = i >> 4, grp = i & 15;
    f32x4 v = *(const f32x4*)(acc + ((size_t)b * HW2 + pix0 + px) * 64 + grp * 4);
    *(f32x4*)(&ts[px][grp * 4]) = v;
  }
  __syncthreads();
  int c = t >> 2, xg = t & 3;
#pragma unroll
  for (int j = 0; j < 4; ++j) {
    int px = xg * 16 + j * 4;
    f32x4 o;
#pragma unroll
    for (int k = 0; k < 4; ++k) o[k] = ts[px + k][c];
    *(f32x4*)(out + (((size_t)b * 64 + c) << 14) + pix0 + px) = o;
  }
}

extern "C" void kernel_launch(void* const* d_in, const int* in_sizes, int n_in,
                              void* d_out, int out_size, void* d_ws, size_t ws_size,
                              hipStream_t stream) {
  const float* x    = (const float*)d_in[0];
  const float* winv = (const float*)d_in[1];
  const float* w1   = (const float*)d_in[2];
  const float* b1   = (const float*)d_in[3];
  const float* nw   = (const float*)d_in[4];
  const float* nb   = (const float*)d_in[5];
  const float* w2   = (const float*)d_in[6];
  const float* b2   = (const float*)d_in[7];
  const float* fw   = (const float*)d_in[8];
  const float* fb   = (const float*)d_in[9];
  const float* gw0  = (const float*)d_in[10];
  const float* gb0  = (const float*)d_in[11];
  const float* gw1  = (const float*)d_in[12];
  const float* gb1  = (const float*)d_in[13];
  const float* ew1  = (const float*)d_in[14];
  const float* eb1  = (const float*)d_in[15];
  const float* ew2  = (const float*)d_in[16];
  const float* eb2  = (const float*)d_in[17];

  char* W = (char*)d_ws;
  ushort_t* A    = (ushort_t*)(W);               // 33.5MB: xhwc, then ycat [y1|y2]
  ushort_t* Bz   = (ushort_t*)(W + 33554432);    // 33.5MB: z [x1|x2]; later acc f32
  float*    accb = (float*)(W + 33554432);
  ushort_t* Ch   = (ushort_t*)(W + 67108864);    // 16.8MB: h / expert hidden
  ushort_t* Dx   = (ushort_t*)(W + 83886080);    // 16.8MB: E / xf
  ushort_t* w3   = (ushort_t*)(W + 100663296);   // [14][72][512] bf16 chunks
  ushort_t* wmm  = (ushort_t*)(W + 101695488);   // winv bf16 [128][128]
  ushort_t* wfu  = (ushort_t*)(W + 101728256);   // fuse bf16 [64][128]
  float* part1 = (float*)(W + 101744640);
  float* kh    = (float*)(W + 101810176);
  float* part2 = (float*)(W + 101812224);
  float* gbuf  = (float*)(W + 101943296);

  float* out = (float*)d_out;
  float* cof = out + (size_t)8 * 64 * HW2;

  const int WS3 = 36864;  // per-conv weight stride (ushorts)
  dim3 cg1(128, 8), cg3(64, 8), rg(32, 8);

  wtrans_kernel<<<2016, 256, 0, stream>>>(w1, w2, ew1, ew2, w3);
  cvt_kernel<<<64, 256, 0, stream>>>(winv, wmm, 16384);
  cvt_kernel<<<32, 256, 0, stream>>>(fw, wfu, 8192);
  xtrans_kernel<<<dim3(1024, 8), 256, 0, stream>>>(x, A);

  // z = winv @ x  (C=128 NHWC): x1=ch0-63, x2=ch64-127
  mm1_kernel<8><<<cg1, 256, 0, stream>>>(A, 128, wmm, nullptr, Bz, 128);

  // hin0(x2): y1 = x1 + x2 + conv2(inorm_half(conv1(x2)))
  conv3_kernel<M_PLAIN, false><<<cg3, 256, 0, stream>>>(Bz, 128, 64, w3 + 0 * WS3, b1,
      Ch, 64, 0, nullptr,0,0, nullptr,0,0, nullptr,0,0, kh, nullptr, 0);
  ireduce_kernel<<<rg, 256, 0, stream>>>(Ch, part1);
  istat_kernel<<<1, 256, 0, stream>>>(part1, nw, nb, kh);
  conv3_kernel<M_ADD2, true><<<cg3, 256, 0, stream>>>(Ch, 64, 0, w3 + 3 * WS3, b2,
      A, 128, 0, Bz, 128, 64, Bz, 128, 0, nullptr,0,0, kh, nullptr, 0);

  // hin2(y1): E = exp(0.8*(2*sigmoid(y1 + conv2(inorm_half(conv1(y1)))) - 1))
  conv3_kernel<M_PLAIN, false><<<cg3, 256, 0, stream>>>(A, 128, 0, w3 + 2 * WS3, b1 + 128,
      Ch, 64, 0, nullptr,0,0, nullptr,0,0, nullptr,0,0, kh, nullptr, 0);
  ireduce_kernel<<<rg, 256, 0, stream>>>(Ch, part1);
  istat_kernel<<<1, 256, 0, stream>>>(part1, nw + 64, nb + 64, kh);
  conv3_kernel<M_SIGEXP, true><<<cg3, 256, 0, stream>>>(Ch, 64, 0, w3 + 5 * WS3, b2 + 128,
      Dx, 64, 0, A, 128, 0, nullptr,0,0, nullptr,0,0, kh, nullptr, 0);

  // hin1(y1): y2 = x2*E + y1 + conv2(inorm_half(conv1(y1)))
  conv3_kernel<M_PLAIN, false><<<cg3, 256, 0, stream>>>(A, 128, 0, w3 + 1 * WS3, b1 + 64,
      Ch, 64, 0, nullptr,0,0, nullptr,0,0, nullptr,0,0, kh, nullptr, 0);
  ireduce_kernel<<<rg, 256, 0, stream>>>(Ch, part1);
  istat_kernel<<<1, 256, 0, stream>>>(part1, nw + 32, nb + 32, kh);
  conv3_kernel<M_COUPLE, true><<<cg3, 256, 0, stream>>>(Ch, 64, 0, w3 + 4 * WS3, b2 + 64,
      A, 128, 64, A, 128, 0, Bz, 128, 64, Dx, 64, 0, kh, nullptr, 0);

  // xf = fuse_w @ [y1;y2] + fb   (into Dx; E is dead)
  mm1_kernel<4><<<cg1, 256, 0, stream>>>(A, 128, wfu, fb, Dx, 64);

  // gating
  preduce_kernel<<<rg, 256, 0, stream>>>(Dx, part2);
  pool2_kernel<<<2, 256, 0, stream>>>(part2, gbuf);
  gate_kernel<<<1, 64, 0, stream>>>(gbuf, gw0, gb0, gw1, gb1, cof);

  // experts: acc(NHWC f32) = sum_e cof_e * (conv2(lrelu(conv1(xf))) + xf)
  for (int e = 0; e < 4; ++e) {
    conv3_kernel<M_LRELU, false><<<cg3, 256, 0, stream>>>(Dx, 64, 0, w3 + (6 + e) * WS3,
        eb1 + e * 64, Ch, 64, 0, nullptr,0,0, nullptr,0,0, nullptr,0,0, kh, cof, e);
    conv3_kernel<M_EACC, false><<<cg3, 256, 0, stream>>>(Ch, 64, 0, w3 + (10 + e) * WS3,
        eb2 + e * 64, (void*)accb, 64, 0, Dx, 64, 0, nullptr,0,0, nullptr,0,0, kh, cof, e);
  }

  nchw_kernel<<<dim3(256, 8), 256, 0, stream>>>(accb, out);
}

// Round 9
// 476.394 us; speedup vs baseline: 1.2590x; 1.2590x over previous
//
#include <hip/hip_runtime.h>
#include <cstddef>

// LfExpert: bf16 MFMA implicit-GEMM. NHWC bf16 activations, fp32 accum.
// R9: revert conv3 to R5 block-staged 16x16 (best measured). Restructure
// experts using cof1+cof2==1: H kernel computes h for the 2 active experts
// (grid z=2, weights via eidx); EFIN stages cof-scaled h twice and writes
// NCHW f32 out directly (kills f32 RMW acc + nchw pass + expert skips).

#define HW2 16384
typedef short short8 __attribute__((ext_vector_type(8)));
typedef float f32x4 __attribute__((ext_vector_type(4)));
typedef unsigned short ushort_t;
typedef unsigned int uint_t;

enum { M_PLAIN = 0, M_ADD2 = 1, M_SIGEXP = 2, M_COUPLE = 3, M_LRELU = 4 };

__device__ __forceinline__ float bf2f(ushort_t u) {
  return __uint_as_float(((uint_t)u) << 16);
}
__device__ __forceinline__ ushort_t f2bf(float f) {
  uint_t u = __float_as_uint(f);
  u += 0x7fffu + ((u >> 16) & 1u);  // RNE
  return (ushort_t)(u >> 16);
}
__device__ __forceinline__ uint_t pack2(float a, float b) {
  return (uint_t)f2bf(a) | ((uint_t)f2bf(b) << 16);
}
__device__ __forceinline__ void ld4bf(const ushort_t* p, float* o) {
  uint2 d = *(const uint2*)p;
  o[0] = bf2f((ushort_t)(d.x & 0xffff)); o[1] = bf2f((ushort_t)(d.x >> 16));
  o[2] = bf2f((ushort_t)(d.y & 0xffff)); o[3] = bf2f((ushort_t)(d.y >> 16));
}
__device__ __forceinline__ void st4bf(ushort_t* p, const float* v) {
  uint2 st; st.x = pack2(v[0], v[1]); st.y = pack2(v[2], v[3]);
  *(uint2*)p = st;
}
__device__ __forceinline__ void gload_lds16(const void* g, void* l) {
  __builtin_amdgcn_global_load_lds(
      (const __attribute__((address_space(1))) void*)g,
      (__attribute__((address_space(3))) void*)l, 16, 0, 0);
}

// ---------- weight transform: [co][ci][3][3] f32 -> chunked bf16 ----------
// chunk c = (tap*2+h)*4+n, 512 ushorts each; lane offset (col*4+krow)*8+e.
__global__ void wtrans_kernel(const float* __restrict__ bw1, const float* __restrict__ bw2,
                              const float* __restrict__ ew1, const float* __restrict__ ew2,
                              ushort_t* __restrict__ wbuf) {
  int idx = blockIdx.x * 256 + threadIdx.x;  // < 516096
  int ci = idx & 63; int co = (idx >> 6) & 63;
  int rest = idx >> 12;            // conv*9 + tap, < 126
  int tap = rest % 9; int conv = rest / 9;
  const float* src;
  if (conv < 3)       src = bw1 + (size_t)conv * 36864;
  else if (conv < 6)  src = bw2 + (size_t)(conv - 3) * 36864;
  else if (conv < 10) src = ew1 + (size_t)(conv - 6) * 36864;
  else                src = ew2 + (size_t)(conv - 10) * 36864;
  float v = src[(co * 64 + ci) * 9 + tap];
  int n = co >> 4, col = co & 15;
  int h = ci >> 5, krow = (ci >> 3) & 3, e = ci & 7;
  int pos = conv * 36864 + (((tap * 2 + h) * 4 + n) << 9) + ((col << 2) + krow) * 8 + e;
  wbuf[pos] = f2bf(v);
}

__global__ void cvt_kernel(const float* __restrict__ s, ushort_t* __restrict__ d, int n) {
  int i = blockIdx.x * 256 + threadIdx.x;
  if (i < n) d[i] = f2bf(s[i]);
}

// ---------- x NCHW f32 -> NHWC bf16 (C=128) ----------
__global__ __launch_bounds__(256) void xtrans_kernel(const float* __restrict__ x,
                                                     ushort_t* __restrict__ xh) {
  int b = blockIdx.y;
  int oct = blockIdx.x >> 6;                    // 0..15
  int p = ((blockIdx.x & 63) << 8) + threadIdx.x;  // 0..16383
  short8 v;
#pragma unroll
  for (int j = 0; j < 8; ++j)
    v[j] = (short)f2bf(x[((size_t)(b * 128 + oct * 8 + j)) * HW2 + p]);
  *(short8*)(xh + ((size_t)b * HW2 + p) * 128 + oct * 8) = v;
}

// ---------- 3x3 conv 64->64 via MFMA, fused epilogues (R5 structure) ----------
// Tile: 16 rows x 16 cols x 64 co per block (wave w owns rows 4w..4w+3).
// LDS slots j=(row*18+xx)*8+octS, octS = oct ^ (xx&7); slot holds 8 ci (16B).
// M_LRELU (expert h): weights/bias picked via eidx[b*2+blockIdx.z], out slot z.
template <int MODE, bool INORM>
__global__ __launch_bounds__(256, 2) void conv3_kernel(
    const ushort_t* __restrict__ in, int icstr, int icoff,
    const ushort_t* __restrict__ wgt, const float* __restrict__ bias,
    void* __restrict__ outv, int ocstr, int ocoff,
    const ushort_t* __restrict__ r1, int r1cstr, int r1off,
    const ushort_t* __restrict__ r2, int r2cstr, int r2off,
    const ushort_t* __restrict__ mul, int mcstr, int moff,
    const float* __restrict__ kh, const int* __restrict__ eidx) {
  int b = blockIdx.y;
  if (MODE == M_LRELU) {
    int e = eidx[b * 2 + (int)blockIdx.z];
    wgt += (size_t)(6 + e) * 36864;   // expert conv1 weights
    bias += e * 64;                   // eb1 row
    outv = (void*)((ushort_t*)outv + (size_t)blockIdx.z * 8388608);  // h slot
  }
  int tile = blockIdx.x;
  int ty0 = (tile >> 3) << 4;   // 8 y-tiles x 16 rows
  int tx0 = (tile & 7) << 4;    // 8 x-tiles x 16 cols
  int t = threadIdx.x;
  int lane = t & 63, w = t >> 6;

  __shared__ __align__(16) ushort_t sm[2592 * 8];  // 41472 B
  char* smb = (char*)sm;

  if (!INORM) {
    // zero-fill OOB halo slots (disjoint from async-loaded slots)
    for (int j = t; j < 2592; j += 256) {
      int row = j / 144, rem = j - row * 144;
      int xx = rem >> 3;
      int gy = ty0 + row - 1, gx = tx0 + xx - 1;
      if ((unsigned)gy >= 128u || (unsigned)gx >= 128u) {
        short8 z = {0, 0, 0, 0, 0, 0, 0, 0};
        *(short8*)(smb + (j << 4)) = z;
      }
    }
    // async staging: linear LDS dest, per-lane global addr carries the swizzle
    for (int k = w; k < 41; k += 4) {
      int j = (k << 6) + lane;
      int row = j / 144, rem = j - row * 144;
      int xx = rem >> 3, octS = rem & 7;
      int oct = octS ^ (xx & 7);
      int gy = ty0 + row - 1, gx = tx0 + xx - 1;
      if (j < 2592 && (unsigned)gy < 128u && (unsigned)gx < 128u) {
        const ushort_t* gp =
            in + ((size_t)b * HW2 + (gy << 7) + gx) * icstr + icoff + oct * 8;
        gload_lds16(gp, smb + (k << 10));
      }
    }
  } else {
    // register staging (instance-norm applied in flight, padding stays 0)
    short8 v[11];
#pragma unroll
    for (int k = 0; k < 11; ++k) {
      int j = t + (k << 8);
      short8 vv = {0, 0, 0, 0, 0, 0, 0, 0};
      if (j < 2592) {
        int row = j / 144, rem = j - row * 144;
        int xx = rem >> 3, octS = rem & 7;
        int oct = octS ^ (xx & 7);
        int gy = ty0 + row - 1, gx = tx0 + xx - 1;
        if ((unsigned)gy < 128u && (unsigned)gx < 128u) {
          vv = *(const short8*)(in + ((size_t)b * HW2 + (gy << 7) + gx) * icstr + icoff + oct * 8);
          if (oct < 4) {  // c<32 normalized; zero-padding NOT normalized
            const float* khp = kh + (b * 32 + oct * 8) * 2;
#pragma unroll
            for (int jq = 0; jq < 8; ++jq) {
              float f = bf2f((ushort_t)vv[jq]);
              vv[jq] = (short)f2bf(f * khp[jq * 2] + khp[jq * 2 + 1]);
            }
          }
        }
      }
      v[k] = vv;
    }
#pragma unroll
    for (int k = 0; k < 11; ++k) {
      int j = t + (k << 8);
      if (j < 2592) *(short8*)(smb + (j << 4)) = v[k];
    }
  }
  __syncthreads();

  int col = lane & 15, krow = lane >> 4;
  int wofs = ((col << 2) + krow) * 8;  // lane offset within 512-ushort chunk
  f32x4 acc[4][4] = {};

#pragma unroll
  for (int tap = 0; tap < 9; ++tap) {
    const int dy = tap / 3, dx = tap - dy * 3;
#pragma unroll
    for (int h = 0; h < 2; ++h) {
      short8 af[4];
      const ushort_t* wbase = wgt + (((tap * 2 + h) * 4) << 9) + wofs;
#pragma unroll
      for (int n = 0; n < 4; ++n) af[n] = *(const short8*)(wbase + (n << 9));
      short8 bfr[4];
#pragma unroll
      for (int s = 0; s < 4; ++s) {
        int row = (w << 2) + s + dy, xx = col + dx;
        bfr[s] = *(const short8*)(smb +
                 (((row * 18 + xx) * 8 + ((h * 4 + krow) ^ (xx & 7))) << 4));
      }
#pragma unroll
      for (int s = 0; s < 4; ++s)
#pragma unroll
        for (int n = 0; n < 4; ++n)
          acc[s][n] = __builtin_amdgcn_mfma_f32_16x16x32_bf16(af[n], bfr[s], acc[s][n], 0, 0, 0);
    }
  }

#pragma unroll
  for (int s = 0; s < 4; ++s) {
    int py = ty0 + (w << 2) + s;
    size_t pix = (size_t)b * HW2 + (py << 7) + tx0 + col;
#pragma unroll
    for (int n = 0; n < 4; ++n) {
      int cb = n * 16 + krow * 4;
      float v[4];
#pragma unroll
      for (int r = 0; r < 4; ++r) v[r] = acc[s][n][r] + bias[cb + r];
      if (MODE == M_PLAIN) {
        st4bf((ushort_t*)outv + pix * ocstr + ocoff + cb, v);
      } else if (MODE == M_ADD2) {
        float a[4], bb[4];
        ld4bf(r1 + pix * r1cstr + r1off + cb, a);
        ld4bf(r2 + pix * r2cstr + r2off + cb, bb);
#pragma unroll
        for (int r = 0; r < 4; ++r) v[r] += a[r] + bb[r];
        st4bf((ushort_t*)outv + pix * ocstr + ocoff + cb, v);
      } else if (MODE == M_SIGEXP) {
        float a[4];
        ld4bf(r1 + pix * r1cstr + r1off + cb, a);
#pragma unroll
        for (int r = 0; r < 4; ++r) {
          float tt = v[r] + a[r];
          float sg = 1.f / (1.f + __expf(-tt));
          v[r] = __expf(1.6f * sg - 0.8f);
        }
        st4bf((ushort_t*)outv + pix * ocstr + ocoff + cb, v);
      } else if (MODE == M_COUPLE) {
        float a[4], bb[4], mm[4];
        ld4bf(r1 + pix * r1cstr + r1off + cb, a);
        ld4bf(r2 + pix * r2cstr + r2off + cb, bb);
        ld4bf(mul + pix * mcstr + moff + cb, mm);
#pragma unroll
        for (int r = 0; r < 4; ++r) v[r] += a[r] + bb[r] * mm[r];
        st4bf((ushort_t*)outv + pix * ocstr + ocoff + cb, v);
      } else if (MODE == M_LRELU) {
#pragma unroll
        for (int r = 0; r < 4; ++r) v[r] = v[r] > 0.f ? v[r] : 0.2f * v[r];
        st4bf((ushort_t*)outv + pix * ocstr + ocoff + cb, v);
      }
    }
  }
}

// ---------- expert finish: out = conv2_e0(c0*h0) + conv2_e1(c1*h1) + bias~ + xf ----------
// 8x16 tile, register staging of cof-scaled h (bf16), two K-passes over one LDS
// buffer, NCHW f32 output written directly (no f32 accumulator round-trip).
__global__ __launch_bounds__(256) void efin_kernel(
    const ushort_t* __restrict__ hbase,   // slot stride 8388608 ushorts
    const ushort_t* __restrict__ xf,      // NHWC bf16, cstr 64
    const ushort_t* __restrict__ wgt14,   // w3 base
    const float* __restrict__ eb2,        // [4][64]
    const int* __restrict__ eidx, const float* __restrict__ cof,
    float* __restrict__ out) {
  int b = blockIdx.y;
  int tile = blockIdx.x;
  int ty0 = (tile >> 3) << 3;   // 16 y-tiles x 8 rows
  int tx0 = (tile & 7) << 4;
  int t = threadIdx.x, lane = t & 63, w = t >> 6;
  int col = lane & 15, krow = lane >> 4;
  __shared__ __align__(16) ushort_t sm[1440 * 8];  // 23040 B
  char* smb = (char*)sm;
  int e0 = eidx[b * 2], e1 = eidx[b * 2 + 1];
  float c0 = cof[b * 4 + e0], c1 = cof[b * 4 + e1];
  int wofs = ((col << 2) + krow) * 8;
  f32x4 acc[2][4] = {};

  for (int s = 0; s < 2; ++s) {
    float cs = s ? c1 : c0;
    const ushort_t* hsrc = hbase + (size_t)s * 8388608;
    const ushort_t* wgt = wgt14 + (size_t)(10 + (s ? e1 : e0)) * 36864;
    if (s) __syncthreads();  // protect LDS before overwrite
    short8 v[6];
#pragma unroll
    for (int k = 0; k < 6; ++k) {
      int j = t + (k << 8);
      short8 vv = {0, 0, 0, 0, 0, 0, 0, 0};
      if (j < 1440) {
        int row = j / 144, rem = j - row * 144;
        int xx = rem >> 3, octS = rem & 7;
        int oct = octS ^ (xx & 7);
        int gy = ty0 + row - 1, gx = tx0 + xx - 1;
        if ((unsigned)gy < 128u && (unsigned)gx < 128u) {
          vv = *(const short8*)(hsrc + ((size_t)b * HW2 + (gy << 7) + gx) * 64 + oct * 8);
#pragma unroll
          for (int jq = 0; jq < 8; ++jq)
            vv[jq] = (short)f2bf(bf2f((ushort_t)vv[jq]) * cs);
        }
      }
      v[k] = vv;
    }
#pragma unroll
    for (int k = 0; k < 6; ++k) {
      int j = t + (k << 8);
      if (j < 1440) *(short8*)(smb + (j << 4)) = v[k];
    }
    __syncthreads();
#pragma unroll
    for (int tap = 0; tap < 9; ++tap) {
      const int dy = tap / 3, dx = tap - dy * 3;
#pragma unroll
      for (int h = 0; h < 2; ++h) {
        short8 af[4];
        const ushort_t* wbase = wgt + (((tap * 2 + h) * 4) << 9) + wofs;
#pragma unroll
        for (int n = 0; n < 4; ++n) af[n] = *(const short8*)(wbase + (n << 9));
        short8 bfr[2];
#pragma unroll
        for (int ss = 0; ss < 2; ++ss) {
          int row = (w << 1) + ss + dy, xx = col + dx;
          bfr[ss] = *(const short8*)(smb +
                   (((row * 18 + xx) * 8 + ((h * 4 + krow) ^ (xx & 7))) << 4));
        }
#pragma unroll
        for (int ss = 0; ss < 2; ++ss)
#pragma unroll
          for (int n = 0; n < 4; ++n)
            acc[ss][n] = __builtin_amdgcn_mfma_f32_16x16x32_bf16(af[n], bfr[ss], acc[ss][n], 0, 0, 0);
      }
    }
  }

#pragma unroll
  for (int ss = 0; ss < 2; ++ss) {
    int py = ty0 + (w << 1) + ss;
    size_t pnh = (size_t)b * HW2 + (py << 7) + tx0 + col;
#pragma unroll
    for (int n = 0; n < 4; ++n) {
      int cb = n * 16 + krow * 4;
      float xv[4];
      ld4bf(xf + pnh * 64 + cb, xv);
#pragma unroll
      for (int r = 0; r < 4; ++r) {
        int c = cb + r;
        float bb = c0 * eb2[e0 * 64 + c] + c1 * eb2[e1 * 64 + c];
        out[(((size_t)b * 64 + c) << 14) + (py << 7) + tx0 + col] =
            acc[ss][n][r] + bb + xv[r];
      }
    }
  }
}

// ---------- 1x1 conv (K=128) via MFMA, software-pipelined ----------
template <int NF>  // NF = NCO/16
__global__ __launch_bounds__(256, 2) void mm1_kernel(
    const ushort_t* __restrict__ in, int icstr,
    const ushort_t* __restrict__ wgt, const float* __restrict__ bias,
    ushort_t* __restrict__ out, int ocstr) {
  int b = blockIdx.y;
  int p0 = blockIdx.x << 7;
  int t = threadIdx.x, lane = t & 63, w = t >> 6;
  int col = lane & 15, krow = lane >> 4;
  size_t pixb = (size_t)b * HW2 + p0 + w * 32;
  // hoist ALL activation loads: 8 independent 16B loads in flight
  short8 bfr[4][2];
#pragma unroll
  for (int kk = 0; kk < 4; ++kk)
#pragma unroll
    for (int s = 0; s < 2; ++s)
      bfr[kk][s] = *(const short8*)(in + (pixb + s * 16 + col) * icstr + kk * 32 + krow * 8);
  f32x4 acc[2][NF] = {};
#pragma unroll
  for (int kk = 0; kk < 4; ++kk) {
#pragma unroll
    for (int n = 0; n < NF; ++n) {
      short8 af = *(const short8*)(wgt + (n * 16 + col) * 128 + kk * 32 + krow * 8);
#pragma unroll
      for (int s = 0; s < 2; ++s)
        acc[s][n] = __builtin_amdgcn_mfma_f32_16x16x32_bf16(af, bfr[kk][s], acc[s][n], 0, 0, 0);
    }
  }
#pragma unroll
  for (int s = 0; s < 2; ++s) {
    size_t pix = pixb + s * 16 + col;
#pragma unroll
    for (int n = 0; n < NF; ++n) {
      int cb = n * 16 + krow * 4;
      float v[4];
#pragma unroll
      for (int r = 0; r < 4; ++r) v[r] = acc[s][n][r] + (bias ? bias[cb + r] : 0.f);
      st4bf(out + pix * ocstr + cb, v);
    }
  }
}

// ---------- instance-norm partial reduce over h (c<32) ----------
__global__ __launch_bounds__(256) void ireduce_kernel(const ushort_t* __restrict__ h,
                                                      float* __restrict__ part) {
  int b = blockIdx.y, chunk = blockIdx.x, t = threadIdx.x;
  int c = t & 31, g = t >> 5;
  float s = 0.f, q = 0.f;
  const ushort_t* base = h + ((size_t)b * HW2 + chunk * 512) * 64 + c;
  for (int i = 0; i < 64; ++i) {
    float f = bf2f(base[(g + i * 8) * 64]);
    s += f; q += f * f;
  }
  __shared__ float ls[8][32], lq[8][32];
  ls[g][c] = s; lq[g][c] = q;
  __syncthreads();
  if (t < 32) {
    float S = 0.f, Q = 0.f;
    for (int gg = 0; gg < 8; ++gg) { S += ls[gg][t]; Q += lq[gg][t]; }
    float* pp = part + ((b * 32 + chunk) * 32 + t) * 2;
    pp[0] = S; pp[1] = Q;
  }
}

__global__ void istat_kernel(const float* __restrict__ part, const float* __restrict__ nw,
                             const float* __restrict__ nb, float* __restrict__ kh) {
  int t = threadIdx.x; if (t >= 256) return;
  int b = t >> 5, c = t & 31;
  float S = 0.f, Q = 0.f;
  for (int ch = 0; ch < 32; ++ch) {
    const float* pp = part + ((b * 32 + ch) * 32 + c) * 2;
    S += pp[0]; Q += pp[1];
  }
  float m = S * (1.f / 16384.f);
  float var = Q * (1.f / 16384.f) - m * m;
  float k = nw[c] * rsqrtf(var + 1e-5f);
  kh[(b * 32 + c) * 2] = k;
  kh[(b * 32 + c) * 2 + 1] = nb[c] - m * k;
}

// ---------- pooling partials (sum, max) over xf ----------
__global__ __launch_bounds__(256) void preduce_kernel(const ushort_t* __restrict__ xf,
                                                      float* __restrict__ part2) {
  int b = blockIdx.y, chunk = blockIdx.x, t = threadIdx.x;
  int c = t & 63, g = t >> 6;
  float s = 0.f, mx = -3.4e38f;
  const ushort_t* base = xf + ((size_t)b * HW2 + chunk * 512) * 64 + c;
  for (int i = 0; i < 128; ++i) {
    float f = bf2f(base[(g + i * 4) * 64]);
    s += f; mx = fmaxf(mx, f);
  }
  __shared__ float ls[4][64], lm[4][64];
  ls[g][c] = s; lm[g][c] = mx;
  __syncthreads();
  if (t < 64) {
    float S = ls[0][t] + ls[1][t] + ls[2][t] + ls[3][t];
    float M = fmaxf(fmaxf(lm[0][t], lm[1][t]), fmaxf(lm[2][t], lm[3][t]));
    float* pp = part2 + ((b * 32 + chunk) * 64 + t) * 2;
    pp[0] = S; pp[1] = M;
  }
}

__global__ void pool2_kernel(const float* __restrict__ part2, float* __restrict__ g) {
  int t = blockIdx.x * blockDim.x + threadIdx.x;
  if (t >= 512) return;
  int b = t >> 6, c = t & 63;
  float S = 0.f, M = -3.4e38f;
  for (int ch = 0; ch < 32; ++ch) {
    const float* pp = part2 + ((b * 32 + ch) * 64 + c) * 2;
    S += pp[0]; M = fmaxf(M, pp[1]);
  }
  g[t] = M + S * (1.f / 16384.f);
}

// ---------- gating (also emits the two active expert indices) ----------
__global__ void gate_kernel(const float* __restrict__ g, const float* __restrict__ gw0,
                            const float* __restrict__ gb0, const float* __restrict__ gw1,
                            const float* __restrict__ gb1, float* __restrict__ cof,
                            int* __restrict__ eidx) {
  int b = threadIdx.x;
  if (b >= 8) return;
  float lg[4], noise[4];
  for (int e = 0; e < 4; ++e) {
    float a0 = gb0[e], a1 = gb1[e];
    for (int c = 0; c < 64; ++c) {
      float gv = g[b * 64 + c];
      a0 += gv * gw0[e * 64 + c];
      a1 += gv * gw1[e * 64 + c];
    }
    lg[e] = a1 > 0.f ? a1 : 0.2f * a1;
    noise[e] = fmaxf(a0, 0.f) + log1pf(expf(-fabsf(a0)));
  }
  float nm = 0.25f * (noise[0] + noise[1] + noise[2] + noise[3]);
  float vs = 0.f;
  for (int e = 0; e < 4; ++e) { float d = noise[e] - nm; vs += d * d; }
  float ns = sqrtf(vs / 3.f);
  float sc[4];
  for (int e = 0; e < 4; ++e) sc[e] = lg[e] + (noise[e] - nm) / ns;
  int i1 = 0;
  for (int e = 1; e < 4; ++e) if (sc[e] > sc[i1]) i1 = e;
  int i2 = -1;
  for (int e = 0; e < 4; ++e) if (e != i1 && (i2 < 0 || sc[e] > sc[i2])) i2 = e;
  float mx = fmaxf(lg[i1], lg[i2]);
  float e1 = expf(lg[i1] - mx), e2 = expf(lg[i2] - mx);
  float d = e1 + e2;
  for (int e = 0; e < 4; ++e) cof[b * 4 + e] = 0.f;
  cof[b * 4 + i1] = e1 / d;
  cof[b * 4 + i2] = e2 / d;
  eidx[b * 2] = i1;
  eidx[b * 2 + 1] = i2;
}

extern "C" void kernel_launch(void* const* d_in, const int* in_sizes, int n_in,
                              void* d_out, int out_size, void* d_ws, size_t ws_size,
                              hipStream_t stream) {
  const float* x    = (const float*)d_in[0];
  const float* winv = (const float*)d_in[1];
  const float* w1   = (const float*)d_in[2];
  const float* b1   = (const float*)d_in[3];
  const float* nw   = (const float*)d_in[4];
  const float* nb   = (const float*)d_in[5];
  const float* w2   = (const float*)d_in[6];
  const float* b2   = (const float*)d_in[7];
  const float* fw   = (const float*)d_in[8];
  const float* fb   = (const float*)d_in[9];
  const float* gw0  = (const float*)d_in[10];
  const float* gb0  = (const float*)d_in[11];
  const float* gw1  = (const float*)d_in[12];
  const float* gb1  = (const float*)d_in[13];
  const float* ew1  = (const float*)d_in[14];
  const float* eb1  = (const float*)d_in[15];
  const float* ew2  = (const float*)d_in[16];
  const float* eb2  = (const float*)d_in[17];

  char* W = (char*)d_ws;
  ushort_t* A    = (ushort_t*)(W);               // 33.5MB: xhwc -> ycat -> h0|h1
  ushort_t* Bz   = (ushort_t*)(W + 33554432);    // 33.5MB: z [x1|x2]
  ushort_t* Ch   = (ushort_t*)(W + 67108864);    // 16.8MB: hin intermediate h
  ushort_t* Dx   = (ushort_t*)(W + 83886080);    // 16.8MB: E / xf
  ushort_t* w3   = (ushort_t*)(W + 100663296);   // [14][72][512] bf16 chunks
  ushort_t* wmm  = (ushort_t*)(W + 101695488);   // winv bf16 [128][128]
  ushort_t* wfu  = (ushort_t*)(W + 101728256);   // fuse bf16 [64][128]
  float* part1 = (float*)(W + 101744640);
  float* kh    = (float*)(W + 101810176);
  float* part2 = (float*)(W + 101812224);
  float* gbuf  = (float*)(W + 101943296);
  int*   eidx  = (int*)(W + 101945344);

  float* out = (float*)d_out;
  float* cof = out + (size_t)8 * 64 * HW2;

  const int WS3 = 36864;  // per-conv weight stride (ushorts)
  dim3 cg1(128, 8), cg3(64, 8), rg(32, 8);

  wtrans_kernel<<<2016, 256, 0, stream>>>(w1, w2, ew1, ew2, w3);
  cvt_kernel<<<64, 256, 0, stream>>>(winv, wmm, 16384);
  cvt_kernel<<<32, 256, 0, stream>>>(fw, wfu, 8192);
  xtrans_kernel<<<dim3(1024, 8), 256, 0, stream>>>(x, A);

  // z = winv @ x  (C=128 NHWC): x1=ch0-63, x2=ch64-127
  mm1_kernel<8><<<cg1, 256, 0, stream>>>(A, 128, wmm, nullptr, Bz, 128);

  // hin0(x2): y1 = x1 + x2 + conv2(inorm_half(conv1(x2)))   (ycat into A)
  conv3_kernel<M_PLAIN, false><<<cg3, 256, 0, stream>>>(Bz, 128, 64, w3 + 0 * WS3, b1,
      Ch, 64, 0, nullptr,0,0, nullptr,0,0, nullptr,0,0, kh, nullptr);
  ireduce_kernel<<<rg, 256, 0, stream>>>(Ch, part1);
  istat_kernel<<<1, 256, 0, stream>>>(part1, nw, nb, kh);
  conv3_kernel<M_ADD2, true><<<cg3, 256, 0, stream>>>(Ch, 64, 0, w3 + 3 * WS3, b2,
      A, 128, 0, Bz, 128, 64, Bz, 128, 0, nullptr,0,0, kh, nullptr);

  // hin2(y1): E = exp(0.8*(2*sigmoid(y1 + conv2(inorm_half(conv1(y1)))) - 1))
  conv3_kernel<M_PLAIN, false><<<cg3, 256, 0, stream>>>(A, 128, 0, w3 + 2 * WS3, b1 + 128,
      Ch, 64, 0, nullptr,0,0, nullptr,0,0, nullptr,0,0, kh, nullptr);
  ireduce_kernel<<<rg, 256, 0, stream>>>(Ch, part1);
  istat_kernel<<<1, 256, 0, stream>>>(part1, nw + 64, nb + 64, kh);
  conv3_kernel<M_SIGEXP, true><<<cg3, 256, 0, stream>>>(Ch, 64, 0, w3 + 5 * WS3, b2 + 128,
      Dx, 64, 0, A, 128, 0, nullptr,0,0, nullptr,0,0, kh, nullptr);

  // hin1(y1): y2 = x2*E + y1 + conv2(inorm_half(conv1(y1)))
  conv3_kernel<M_PLAIN, false><<<cg3, 256, 0, stream>>>(A, 128, 0, w3 + 1 * WS3, b1 + 64,
      Ch, 64, 0, nullptr,0,0, nullptr,0,0, nullptr,0,0, kh, nullptr);
  ireduce_kernel<<<rg, 256, 0, stream>>>(Ch, part1);
  istat_kernel<<<1, 256, 0, stream>>>(part1, nw + 32, nb + 32, kh);
  conv3_kernel<M_COUPLE, true><<<cg3, 256, 0, stream>>>(Ch, 64, 0, w3 + 4 * WS3, b2 + 64,
      A, 128, 64, A, 128, 0, Bz, 128, 64, Dx, 64, 0, kh, nullptr);

  // xf = fuse_w @ [y1;y2] + fb   (into Dx; E is dead)
  mm1_kernel<4><<<cg1, 256, 0, stream>>>(A, 128, wfu, fb, Dx, 64);

  // gating
  preduce_kernel<<<rg, 256, 0, stream>>>(Dx, part2);
  pool2_kernel<<<2, 256, 0, stream>>>(part2, gbuf);
  gate_kernel<<<1, 64, 0, stream>>>(gbuf, gw0, gb0, gw1, gb1, cof, eidx);

  // experts: h_z = lrelu(conv1_{e_z}(xf)) for the 2 active experts (A reused)
  conv3_kernel<M_LRELU, false><<<dim3(64, 8, 2), 256, 0, stream>>>(Dx, 64, 0, w3, eb1,
      A, 64, 0, nullptr,0,0, nullptr,0,0, nullptr,0,0, kh, eidx);
  // out = conv2_e0(c0*h0) + conv2_e1(c1*h1) + (c0*b0+c1*b1) + xf  (NCHW direct)
  efin_kernel<<<cg1, 256, 0, stream>>>(A, Dx, w3, eb2, eidx, cof, out);
}